// Round 2
// baseline (246.792 us; speedup 1.0000x reference)
//
#include <hip/hip_runtime.h>
#include <hip/hip_bf16.h>
#include <stdint.h>

typedef unsigned long long u64;
typedef unsigned int u32;

#define R_N 1000
#define K_N 80
#define TOPK_N 100
#define OUT_W 87          // 4 box + 1 score + 1 cls + 81 full scores
#define IMG_W_ 1333.0f
#define IMG_H_ 800.0f
#define LCAP 7936         // LDS-staged candidate cap (keeps static LDS < 64KB)

// ---- runtime input-dtype detection -----------------------------------------
// softmax scores are strictly positive: a genuine bf16 buffer has NO u16 with
// the sign bit set. An f32 buffer read as u16 has ~half of its even-indexed
// (mantissa-fragment) words with bit15 set. Scan first 32 u64 (128 u16):
// P(f32 undetected) ~ 2^-64.
__device__ __forceinline__ bool detect_f32(const void* scores) {
    const u64* p = (const u64*)scores;
    u64 acc = 0;
#pragma unroll
    for (int i = 0; i < 32; ++i) acc |= p[i];
    return (acc & 0x8000800080008000ull) != 0ull;
}
__device__ __forceinline__ float ldv(const void* b, int i, bool f32m) {
    if (f32m) return ((const float*)b)[i];
    u32 u = (u32)(((const unsigned short*)b)[i]) << 16;
    return __uint_as_float(u);
}
__device__ __forceinline__ void stv(void* o, int i, float v, bool f32m) {
    if (f32m) ((float*)o)[i] = v;
    else ((__hip_bfloat16*)o)[i] = __float2bfloat16(v);
}

// order-preserving f32 -> u32 (monotone: a<b  <=>  ord(a)<ord(b))
__device__ __forceinline__ u32 f32_order(float f) {
    u32 u = __float_as_uint(f);
    return u ^ (((u32)((int)u >> 31)) | 0x80000000u);
}
__device__ __forceinline__ float f32_unorder(u32 o) {
    u32 u = (o & 0x80000000u) ? (o ^ 0x80000000u) : ~o;
    return __uint_as_float(u);
}

// ---------------- kernel 1: threshold = min(0.05, (mean(fg)+max(fg))/2), zero counter
__global__ __launch_bounds__(1024) void k_prep(const void* __restrict__ scores,
                                               float* __restrict__ hdr) {
    __shared__ float s_sum[16], s_max[16];
    const int tid = threadIdx.x;
    const bool f32m = detect_f32(scores);
    float sum = 0.f, mx = -1e30f;
    for (int t = tid; t < R_N * (K_N + 1); t += 1024) {
        if ((t % (K_N + 1)) == K_N) continue;   // skip background column
        float v = ldv(scores, t, f32m);
        sum += v;
        mx = fmaxf(mx, v);
    }
#pragma unroll
    for (int off = 32; off > 0; off >>= 1) {
        sum += __shfl_down(sum, off);
        mx = fmaxf(mx, __shfl_down(mx, off));
    }
    if ((tid & 63) == 0) { s_sum[tid >> 6] = sum; s_max[tid >> 6] = mx; }
    __syncthreads();
    if (tid == 0) {
        float S = 0.f, M = -1e30f;
        for (int w = 0; w < 16; ++w) { S += s_sum[w]; M = fmaxf(M, s_max[w]); }
        float mean = S / (float)(R_N * K_N);
        hdr[0] = fminf(0.05f, 0.5f * (mean + M));
        ((int*)hdr)[1] = 0;   // candidate counter
    }
}

// ---------------- kernel 2: per-class compact -> stable sort -> greedy NMS -> emit candidates
__global__ __launch_bounds__(256) void k_nms(const void* __restrict__ boxes,
                                             const void* __restrict__ scores,
                                             float* __restrict__ hdr,
                                             u64* __restrict__ cand, int cand_cap) {
    const int c = blockIdx.x;
    const int tid = threadIdx.x;
    __shared__ int s_n;
    __shared__ u64 u_key[R_N];
    __shared__ float u_x1[R_N], u_y1[R_N], u_x2[R_N], u_y2[R_N];
    __shared__ u64 s_key[R_N];
    __shared__ float s_x1[R_N], s_y1[R_N], s_x2[R_N], s_y2[R_N], s_area[R_N];
    __shared__ unsigned char s_keep[R_N];

    const bool f32m = detect_f32(scores);
    const float thres = hdr[0];
    if (tid == 0) s_n = 0;
    __syncthreads();

    // compact valid boxes (score > thres); key encodes (score desc, orig index asc)
    for (int r = tid; r < R_N; r += 256) {
        float s = ldv(scores, r * (K_N + 1) + c, f32m);
        if (s > thres) {
            int slot = atomicAdd(&s_n, 1);
            u_key[slot] = ((u64)f32_order(s) << 32) | (u64)(u32)(R_N - 1 - r);
            int bb = r * (K_N * 4) + c * 4;
            u_x1[slot] = fminf(fmaxf(ldv(boxes, bb + 0, f32m), 0.f), IMG_W_);
            u_y1[slot] = fminf(fmaxf(ldv(boxes, bb + 1, f32m), 0.f), IMG_H_);
            u_x2[slot] = fminf(fmaxf(ldv(boxes, bb + 2, f32m), 0.f), IMG_W_);
            u_y2[slot] = fminf(fmaxf(ldv(boxes, bb + 3, f32m), 0.f), IMG_H_);
        }
    }
    __syncthreads();
    const int n = s_n;

    // rank by counting (keys are distinct) -> scatter into sorted arrays
    for (int j = tid; j < n; j += 256) {
        u64 kj = u_key[j];
        int rank = 0;
        for (int k = 0; k < n; ++k) rank += (u_key[k] > kj) ? 1 : 0;
        s_key[rank] = kj;
        float x1 = u_x1[j], y1 = u_y1[j], x2 = u_x2[j], y2 = u_y2[j];
        s_x1[rank] = x1; s_y1[rank] = y1; s_x2[rank] = x2; s_y2[rank] = y2;
        s_area[rank] = fmaxf(x2 - x1, 0.f) * fmaxf(y2 - y1, 0.f);
        s_keep[rank] = 1;
    }

    // greedy sequential NMS (reference semantics: suppressed boxes don't suppress)
    for (int i = 0; i < n - 1; ++i) {
        __syncthreads();
        if (!s_keep[i]) continue;     // uniform branch: all threads read same LDS byte
        const float x1i = s_x1[i], y1i = s_y1[i], x2i = s_x2[i], y2i = s_y2[i], ai = s_area[i];
        for (int j = i + 1 + tid; j < n; j += 256) {
            if (!s_keep[j]) continue;
            float xx1 = fmaxf(x1i, s_x1[j]);
            float yy1 = fmaxf(y1i, s_y1[j]);
            float xx2 = fminf(x2i, s_x2[j]);
            float yy2 = fminf(y2i, s_y2[j]);
            float inter = fmaxf(xx2 - xx1, 0.f) * fmaxf(yy2 - yy1, 0.f);
            float uni = ai + s_area[j] - inter;
            float iou = inter / fmaxf(uni, 1e-9f);
            if (iou > 0.5f) s_keep[j] = 0;
        }
    }
    __syncthreads();

    // emit kept candidates: key = score(32) | inv_flat(17) | prop(10)
    int* cnt = ((int*)hdr) + 1;
    for (int i = tid; i < n; i += 256) {
        if (s_keep[i]) {
            int slot = atomicAdd(cnt, 1);
            if (slot < cand_cap) {
                u32 osc = (u32)(s_key[i] >> 32);
                int r = (R_N - 1) - (int)(s_key[i] & 0xFFFFFFFFull);
                int flat = c * R_N + i;           // i == sorted position
                cand[slot] = ((u64)osc << 27) | ((u64)(u32)(131071 - flat) << 10) | (u64)(u32)r;
            }
        }
    }
}

// ---------------- kernel 3: top-100 by (score desc, flat idx asc), write 100x87 output
__global__ __launch_bounds__(1024) void k_topk(const void* __restrict__ boxes,
                                               const void* __restrict__ scores,
                                               const float* __restrict__ hdr,
                                               const u64* __restrict__ cand, int cand_cap,
                                               void* __restrict__ out) {
    __shared__ u64 s_cand[LCAP];
    __shared__ u64 s_sel[TOPK_N];
    __shared__ u64 s_red[16];
    const int tid = threadIdx.x;
    const bool f32m = detect_f32(scores);
    int M = ((const int*)hdr)[1];
    if (M > cand_cap) M = cand_cap;
    const bool lds = (M <= LCAP);
    if (lds) for (int t = tid; t < M; t += 1024) s_cand[t] = cand[t];
    if (tid < TOPK_N) s_sel[tid] = 0;
    __syncthreads();

    u64 prev = ~0ull;   // keys are unique (flat idx unique) -> strict-descending selection
    for (int k = 0; k < TOPK_N; ++k) {
        u64 best = 0;
        for (int t = tid; t < M; t += 1024) {
            u64 v = lds ? s_cand[t] : cand[t];
            if (v < prev && v > best) best = v;
        }
#pragma unroll
        for (int off = 32; off > 0; off >>= 1) {
            u64 o = __shfl_down(best, off);
            if (o > best) best = o;
        }
        if ((tid & 63) == 0) s_red[tid >> 6] = best;
        __syncthreads();
        if (tid == 0) {
            u64 b = 0;
            for (int w = 0; w < 16; ++w) if (s_red[w] > b) b = s_red[w];
            s_sel[k] = b;
        }
        __syncthreads();
        prev = s_sel[k];
        if (prev == 0) break;   // uniform: remaining s_sel stay 0 -> zero rows
    }
    __syncthreads();

    for (int e = tid; e < TOPK_N * OUT_W; e += 1024) {
        int row = e / OUT_W, col = e - row * OUT_W;
        u64 key = s_sel[row];
        float val = 0.f;
        if (key != 0ull) {
            int flat = 131071 - (int)((key >> 10) & 0x1FFFFull);
            int cls = flat / R_N;
            int prop = (int)(key & 0x3FFull);
            if (col < 4) {
                float b = ldv(boxes, prop * (K_N * 4) + cls * 4 + col, f32m);
                float lim = (col & 1) ? IMG_H_ : IMG_W_;
                val = fminf(fmaxf(b, 0.f), lim);
            } else if (col == 4) {
                val = f32_unorder((u32)((key >> 27) & 0xFFFFFFFFull));
            } else if (col == 5) {
                val = (float)cls;
            } else {
                val = ldv(scores, prop * (K_N + 1) + (col - 6), f32m);
            }
        }
        stv(out, e, val, f32m);
    }
}

extern "C" void kernel_launch(void* const* d_in, const int* in_sizes, int n_in,
                              void* d_out, int out_size, void* d_ws, size_t ws_size,
                              hipStream_t stream) {
    const void* boxes = d_in[0];
    const void* scores = d_in[1];
    float* hdr = (float*)d_ws;                       // [0]=thres(f32), [1]=cand count(i32)
    u64* cand = (u64*)((char*)d_ws + 16);
    long long cap = ((long long)ws_size - 16) / 8;
    if (cap > 80000) cap = 80000;
    if (cap < 0) cap = 0;
    int cand_cap = (int)cap;

    k_prep<<<1, 1024, 0, stream>>>(scores, hdr);
    k_nms<<<K_N, 256, 0, stream>>>(boxes, scores, hdr, cand, cand_cap);
    k_topk<<<1, 1024, 0, stream>>>(boxes, scores, hdr, cand, cand_cap, d_out);
}

// Round 3
// 147.224 us; speedup vs baseline: 1.6763x; 1.6763x over previous
//
#include <hip/hip_runtime.h>
#include <hip/hip_bf16.h>
#include <stdint.h>

typedef unsigned long long u64;
typedef unsigned int u32;

#define R_N 1000
#define K_N 80
#define NCOL 81           // K_N + 1 (background col)
#define TOPK_N 100
#define OUT_W 87          // 4 box + 1 score + 1 cls + 81 full scores
#define IMG_W_ 1333.0f
#define IMG_H_ 800.0f
#define CSTR 100          // per-class candidate stride (top-100/class is provably sufficient)
#define NQUAD ((R_N * NCOL) / 4)   // 20250 quads of scores

// ---- runtime input-dtype detection (proven in round 2: inputs are f32, but keep adaptive) ----
__device__ __forceinline__ bool detect_f32(const void* scores) {
    const u64* p = (const u64*)scores;
    u64 acc = 0;
#pragma unroll
    for (int i = 0; i < 32; ++i) acc |= p[i];
    return (acc & 0x8000800080008000ull) != 0ull;   // softmax scores > 0 => no sign bits in bf16
}
__device__ __forceinline__ float ldv(const void* b, int i, bool f32m) {
    if (f32m) return ((const float*)b)[i];
    return __uint_as_float((u32)(((const unsigned short*)b)[i]) << 16);
}
__device__ __forceinline__ void stv(void* o, int i, float v, bool f32m) {
    if (f32m) ((float*)o)[i] = v;
    else ((__hip_bfloat16*)o)[i] = __float2bfloat16(v);
}
__device__ __forceinline__ float4 ld4(const void* b, int i, bool f32m) {  // i % 4 == 0
    if (f32m) return ((const float4*)b)[i >> 2];
    ushort4 u = ((const ushort4*)b)[i >> 2];
    float4 f;
    f.x = __uint_as_float((u32)u.x << 16); f.y = __uint_as_float((u32)u.y << 16);
    f.z = __uint_as_float((u32)u.z << 16); f.w = __uint_as_float((u32)u.w << 16);
    return f;
}
// order-preserving f32 <-> u32
__device__ __forceinline__ u32 f32_order(float f) {
    u32 u = __float_as_uint(f);
    return u ^ (((u32)((int)u >> 31)) | 0x80000000u);
}
__device__ __forceinline__ float f32_unorder(u32 o) {
    u32 u = (o & 0x80000000u) ? (o ^ 0x80000000u) : ~o;
    return __uint_as_float(u);
}

// ---------------- kernel 1: 80-block partial (sum,max) of fg scores + zero d_out -------------
// Deterministic: fixed-tree partials per block, written to hdr[2b],hdr[2b+1]; no atomics.
__global__ __launch_bounds__(256) void k_stat(const void* __restrict__ scores,
                                              float* __restrict__ hdr,
                                              void* __restrict__ out_p) {
    const int b = blockIdx.x, tid = threadIdx.x;
    const bool f32m = detect_f32(scores);

    // zero output slice (rows beyond candidate count must be zero; winners overwrite later)
    const int zn = f32m ? (TOPK_N * OUT_W) : (TOPK_N * OUT_W / 2);  // int-granular zero fill
    for (int t = b * 256 + tid; t < zn; t += K_N * 256) ((int*)out_p)[t] = 0;

    float sum = 0.f, mx = -1e30f;
    int q = b * 256 + tid;                 // one quad per thread (80*256 = 20480 >= 20250)
    if (q < NQUAD) {
        float4 v = ld4(scores, q * 4, f32m);
        int m = (q * 4) % NCOL;
        float vv[4] = {v.x, v.y, v.z, v.w};
#pragma unroll
        for (int e = 0; e < 4; ++e) {
            int mm = m + e; if (mm >= NCOL) mm -= NCOL;
            if (mm != K_N) { sum += vv[e]; mx = fmaxf(mx, vv[e]); }
        }
    }
#pragma unroll
    for (int off = 32; off > 0; off >>= 1) {
        sum += __shfl_down(sum, off);
        mx = fmaxf(mx, __shfl_down(mx, off));
    }
    __shared__ float s_sum[4], s_max[4];
    if ((tid & 63) == 0) { s_sum[tid >> 6] = sum; s_max[tid >> 6] = mx; }
    __syncthreads();
    if (tid == 0) {
        float S = s_sum[0] + s_sum[1] + s_sum[2] + s_sum[3];
        float M = fmaxf(fmaxf(s_sum[0] == s_sum[0] ? s_max[0] : s_max[0], s_max[1]),
                        fmaxf(s_max[2], s_max[3]));
        hdr[2 * b] = S;
        hdr[2 * b + 1] = M;
    }
}

__device__ __forceinline__ float load_thres(const float* hdr) {
    float S = 0.f, M = -1e30f;
    for (int b = 0; b < K_N; ++b) { S += hdr[2 * b]; M = fmaxf(M, hdr[2 * b + 1]); }
    return fminf(0.05f, 0.5f * (S / (float)(R_N * K_N) + M));
}

// ---------------- kernel 2: one WAVE per class: compact -> sort -> greedy NMS -> emit --------
// Single-wave block => every __syncthreads() is just a waitcnt (no multi-wave barrier cost).
__global__ __launch_bounds__(64) void k_nms(const void* __restrict__ boxes,
                                            const void* __restrict__ scores,
                                            const float* __restrict__ hdr,
                                            u64* __restrict__ cand) {
    const int c = blockIdx.x, lane = threadIdx.x;
    __shared__ float sc[R_N];
    __shared__ u64 u_key[R_N];
    __shared__ float u_x1[R_N], u_y1[R_N], u_x2[R_N], u_y2[R_N];
    __shared__ u64 s_key[R_N];
    __shared__ float s_x1[R_N], s_y1[R_N], s_x2[R_N], s_y2[R_N], s_area[R_N];
    __shared__ int s_keep[R_N];

    const bool f32m = detect_f32(scores);
    const float thres = load_thres(hdr);

    // stage score column c (global loads fully pipelined, independent)
    for (int r = lane; r < R_N; r += 64) sc[r] = ldv(scores, r * NCOL + c, f32m);
    __syncthreads();

    // ballot-based stream compaction of valid boxes (key: score desc, orig idx asc)
    int n = 0;
    const u64 below = (lane == 0) ? 0ull : (~0ull >> (64 - lane));
    for (int r0 = 0; r0 < R_N; r0 += 64) {
        int r = r0 + lane;
        bool pred = (r < R_N) && (sc[r] > thres);
        u64 m = __ballot(pred);
        if (pred) {
            int slot = n + __popcll(m & below);
            float s = sc[r];
            u_key[slot] = ((u64)f32_order(s) << 32) | (u64)(u32)(R_N - 1 - r);
            float4 bx = ld4(boxes, r * (K_N * 4) + c * 4, f32m);
            u_x1[slot] = fminf(fmaxf(bx.x, 0.f), IMG_W_);
            u_y1[slot] = fminf(fmaxf(bx.y, 0.f), IMG_H_);
            u_x2[slot] = fminf(fmaxf(bx.z, 0.f), IMG_W_);
            u_y2[slot] = fminf(fmaxf(bx.w, 0.f), IMG_H_);
        }
        n += __popcll(m);
    }
    __syncthreads();

    // counting-rank sort (keys distinct); inner reads are wave-broadcast
    for (int j = lane; j < n; j += 64) {
        u64 kj = u_key[j];
        int rank = 0;
        for (int k = 0; k < n; ++k) rank += (u_key[k] > kj) ? 1 : 0;
        float x1 = u_x1[j], y1 = u_y1[j], x2 = u_x2[j], y2 = u_y2[j];
        s_key[rank] = kj;
        s_x1[rank] = x1; s_y1[rank] = y1; s_x2[rank] = x2; s_y2[rank] = y2;
        s_area[rank] = fmaxf(x2 - x1, 0.f) * fmaxf(y2 - y1, 0.f);
        s_keep[rank] = 1;
    }
    __syncthreads();

    // greedy sequential NMS; per-iteration barrier is single-wave (cheap)
    for (int i = 0; i < n - 1; ++i) {
        __syncthreads();
        if (!s_keep[i]) continue;          // wave-uniform broadcast read
        const float x1i = s_x1[i], y1i = s_y1[i], x2i = s_x2[i], y2i = s_y2[i], ai = s_area[i];
        for (int j = i + 1 + lane; j < n; j += 64) {
            if (!s_keep[j]) continue;
            float xx1 = fmaxf(x1i, s_x1[j]);
            float yy1 = fmaxf(y1i, s_y1[j]);
            float xx2 = fminf(x2i, s_x2[j]);
            float yy2 = fminf(y2i, s_y2[j]);
            float inter = fmaxf(xx2 - xx1, 0.f) * fmaxf(yy2 - yy1, 0.f);
            float uni = ai + s_area[j] - inter;
            if (inter / fmaxf(uni, 1e-9f) > 0.5f) s_keep[j] = 0;
        }
    }
    __syncthreads();

    // emit first <=100 kept (exact for global top-100), zero-pad the rest of the class slots
    int kb = 0;
    for (int j0 = 0; j0 < n; j0 += 64) {
        int j = j0 + lane;
        bool kp = (j < n) && (s_keep[j] != 0);
        u64 m = __ballot(kp);
        int kr = kb + __popcll(m & below);
        if (kp && kr < CSTR) {
            u32 osc = (u32)(s_key[j] >> 32);
            int rr = (R_N - 1) - (int)(s_key[j] & 0xFFFFFFFFull);
            int flat = c * R_N + j;        // j == sorted position
            cand[c * CSTR + kr] = ((u64)osc << 27) | ((u64)(u32)(131071 - flat) << 10) | (u64)(u32)rr;
        }
        kb += __popcll(m);
    }
    if (kb > CSTR) kb = CSTR;
    for (int k = kb + lane; k < CSTR; k += 64) cand[c * CSTR + k] = 0;
}

// ---------------- kernel 3: exact global rank via 80 binary searches; winners write rows -----
__global__ __launch_bounds__(256) void k_rank(const void* __restrict__ boxes,
                                              const void* __restrict__ scores,
                                              const u64* __restrict__ cand,
                                              void* __restrict__ out_p) {
    __shared__ u64 keysL[K_N * CSTR];      // 8000 keys, 64000 B
    const int c = blockIdx.x, tid = threadIdx.x;
    const bool f32m = detect_f32(scores);

    for (int t = tid; t < K_N * CSTR; t += 256) keysL[t] = cand[t];
    __syncthreads();

    u64 x = (tid < CSTR) ? keysL[c * CSTR + tid] : 0ull;
    if (x != 0ull) {
        // global rank = sum over classes of (# keys > x); each class list is descending, 0-padded
        int rank = 0;
        for (int cc = 0; cc < K_N; ++cc) {
            const u64* L = keysL + cc * CSTR;
            int lo = 0, hi = CSTR;
            while (lo < hi) { int mid = (lo + hi) >> 1; if (L[mid] > x) lo = mid + 1; else hi = mid; }
            rank += lo;
        }
        if (rank < TOPK_N) {
            int prop = (int)(x & 0x3FFull);
            float score = f32_unorder((u32)((x >> 27) & 0xFFFFFFFFull));
            int ob = rank * OUT_W;
            float4 bx = ld4(boxes, prop * (K_N * 4) + c * 4, f32m);
            stv(out_p, ob + 0, fminf(fmaxf(bx.x, 0.f), IMG_W_), f32m);
            stv(out_p, ob + 1, fminf(fmaxf(bx.y, 0.f), IMG_H_), f32m);
            stv(out_p, ob + 2, fminf(fmaxf(bx.z, 0.f), IMG_W_), f32m);
            stv(out_p, ob + 3, fminf(fmaxf(bx.w, 0.f), IMG_H_), f32m);
            stv(out_p, ob + 4, score, f32m);
            stv(out_p, ob + 5, (float)c, f32m);
            const int sb = prop * NCOL;
#pragma unroll 9
            for (int j = 0; j < NCOL; ++j)
                stv(out_p, ob + 6 + j, ldv(scores, sb + j, f32m), f32m);
        }
    }
}

extern "C" void kernel_launch(void* const* d_in, const int* in_sizes, int n_in,
                              void* d_out, int out_size, void* d_ws, size_t ws_size,
                              hipStream_t stream) {
    const void* boxes = d_in[0];
    const void* scores = d_in[1];
    float* hdr = (float*)d_ws;                        // 160 f32 partials (sum,max) x 80 blocks
    u64* cand = (u64*)((char*)d_ws + 1024);           // 80*100 u64 = 64000 B

    k_stat<<<K_N, 256, 0, stream>>>(scores, hdr, d_out);
    k_nms<<<K_N, 64, 0, stream>>>(boxes, scores, hdr, cand);
    k_rank<<<K_N, 256, 0, stream>>>(boxes, scores, cand, d_out);
}

// Round 4
// 141.475 us; speedup vs baseline: 1.7444x; 1.0406x over previous
//
#include <hip/hip_runtime.h>
#include <hip/hip_bf16.h>
#include <stdint.h>

typedef unsigned long long u64;
typedef unsigned int u32;

#define R_N 1000
#define K_N 80
#define NCOL 81           // K_N + 1 (background col)
#define TOPK_N 100
#define OUT_W 87          // 4 box + 1 score + 1 cls + 81 full scores
#define IMG_W_ 1333.0f
#define IMG_H_ 800.0f
#define CSTR 100          // per-class candidate stride (top-100/class provably sufficient)
#define NQUAD ((R_N * NCOL) / 4)
#define NMAX 448          // fast-path NMS cap (expected n ~ 60-100)
#define WMAX 7            // ceil(NMAX/64)

// ---- runtime input-dtype detection (round 2 proved f32; keep the shield) ----
__device__ __forceinline__ bool detect_f32(const void* scores) {
    const u64* p = (const u64*)scores;
    u64 acc = 0;
#pragma unroll
    for (int i = 0; i < 32; ++i) acc |= p[i];
    return (acc & 0x8000800080008000ull) != 0ull;
}
__device__ __forceinline__ float ldv(const void* b, int i, bool f32m) {
    if (f32m) return ((const float*)b)[i];
    return __uint_as_float((u32)(((const unsigned short*)b)[i]) << 16);
}
__device__ __forceinline__ void stv(void* o, int i, float v, bool f32m) {
    if (f32m) ((float*)o)[i] = v;
    else ((__hip_bfloat16*)o)[i] = __float2bfloat16(v);
}
__device__ __forceinline__ float4 ld4(const void* b, int i, bool f32m) {  // i % 4 == 0
    if (f32m) return ((const float4*)b)[i >> 2];
    ushort4 u = ((const ushort4*)b)[i >> 2];
    float4 f;
    f.x = __uint_as_float((u32)u.x << 16); f.y = __uint_as_float((u32)u.y << 16);
    f.z = __uint_as_float((u32)u.z << 16); f.w = __uint_as_float((u32)u.w << 16);
    return f;
}
__device__ __forceinline__ u32 f32_order(float f) {
    u32 u = __float_as_uint(f);
    return u ^ (((u32)((int)u >> 31)) | 0x80000000u);
}
__device__ __forceinline__ float f32_unorder(u32 o) {
    u32 u = (o & 0x80000000u) ? (o ^ 0x80000000u) : ~o;
    return __uint_as_float(u);
}

// ---------------- kernel 1: partial (sum,max) of fg scores per block + zero d_out ------------
__global__ __launch_bounds__(256) void k_stat(const void* __restrict__ scores,
                                              float* __restrict__ hdr,
                                              void* __restrict__ out_p) {
    const int b = blockIdx.x, tid = threadIdx.x;
    const bool f32m = detect_f32(scores);

    const int zn = f32m ? (TOPK_N * OUT_W) : (TOPK_N * OUT_W / 2);
    for (int t = b * 256 + tid; t < zn; t += K_N * 256) ((int*)out_p)[t] = 0;

    float sum = 0.f, mx = -1e30f;
    int q = b * 256 + tid;
    if (q < NQUAD) {
        float4 v = ld4(scores, q * 4, f32m);
        int m = (q * 4) % NCOL;
        float vv[4] = {v.x, v.y, v.z, v.w};
#pragma unroll
        for (int e = 0; e < 4; ++e) {
            int mm = m + e; if (mm >= NCOL) mm -= NCOL;
            if (mm != K_N) { sum += vv[e]; mx = fmaxf(mx, vv[e]); }
        }
    }
#pragma unroll
    for (int off = 32; off > 0; off >>= 1) {
        sum += __shfl_down(sum, off);
        mx = fmaxf(mx, __shfl_down(mx, off));
    }
    __shared__ float s_sum[4], s_max[4];
    if ((tid & 63) == 0) { s_sum[tid >> 6] = sum; s_max[tid >> 6] = mx; }
    __syncthreads();
    if (tid == 0) {
        hdr[2 * b] = s_sum[0] + s_sum[1] + s_sum[2] + s_sum[3];
        hdr[2 * b + 1] = fmaxf(fmaxf(s_max[0], s_max[1]), fmaxf(s_max[2], s_max[3]));
    }
}

__device__ __forceinline__ float load_thres(const float* hdr) {
    float S = 0.f, M = -1e30f;
    for (int b = 0; b < K_N; ++b) { S += hdr[2 * b]; M = fmaxf(M, hdr[2 * b + 1]); }
    return fminf(0.05f, 0.5f * (S / (float)(R_N * K_N) + M));
}

// ---------------- kernel 2: one wave/class: compact -> sort -> bitmask NMS -> emit -----------
__global__ __launch_bounds__(64) void k_nms(const void* __restrict__ boxes,
                                            const void* __restrict__ scores,
                                            const float* __restrict__ hdr,
                                            u64* __restrict__ cand) {
    const int c = blockIdx.x, lane = threadIdx.x;
    __shared__ u64 key_s[R_N];                 //  8000 B sorted keys
    __shared__ float4 bx4[R_N];                // 16000 B sorted clipped boxes (AoS)
    __shared__ float area_s[R_N];              //  4000 B
    __shared__ char poolA[NMAX * WMAX * 8];    // 25088 B: ukey -> Mrow (fast) / keep (fallback)
    __shared__ float sc[R_N];                  //  4000 B staged score column
    __shared__ u64 keep_words[16];

    const bool f32m = detect_f32(scores);
    const float thres = load_thres(hdr);

    // stage score column c (independent global loads, one waitcnt)
    for (int r = lane; r < R_N; r += 64) sc[r] = ldv(scores, r * NCOL + c, f32m);
    __syncthreads();

    // ballot stream-compaction: keys only (score desc, orig idx asc)
    u64* ukey = (u64*)poolA;
    int n = 0;
    const u64 below = (lane == 0) ? 0ull : (~0ull >> (64 - lane));
    for (int r0 = 0; r0 < R_N; r0 += 64) {
        int r = r0 + lane;
        bool pred = (r < R_N) && (sc[r] > thres);
        u64 m = __ballot(pred);
        if (pred) {
            int slot = n + __popcll(m & below);
            ukey[slot] = ((u64)f32_order(sc[r]) << 32) | (u64)(u32)(R_N - 1 - r);
        }
        n += __popcll(m);
    }
    __syncthreads();

    // counting-rank sort; gather + clip boxes from global at sorted position
    for (int j = lane; j < n; j += 64) {
        u64 kj = ukey[j];
        int rank = 0;
        for (int k = 0; k < n; ++k) rank += (ukey[k] > kj) ? 1 : 0;
        int r = (R_N - 1) - (int)(kj & 0xFFFFFFFFull);
        float4 b = ld4(boxes, r * (K_N * 4) + c * 4, f32m);
        float x1 = fminf(fmaxf(b.x, 0.f), IMG_W_);
        float y1 = fminf(fmaxf(b.y, 0.f), IMG_H_);
        float x2 = fminf(fmaxf(b.z, 0.f), IMG_W_);
        float y2 = fminf(fmaxf(b.w, 0.f), IMG_H_);
        key_s[rank] = kj;
        bx4[rank] = make_float4(x1, y1, x2, y2);
        area_s[rank] = fmaxf(x2 - x1, 0.f) * fmaxf(y2 - y1, 0.f);
    }
    __syncthreads();

    if (n <= NMAX) {
        // ---- fast path: suppression bit-matrix (throughput) + register propagation (latency)
        const int W = (n + 63) >> 6;
        u64* Mrow = (u64*)poolA;               // ukey dead after sort
        for (int w = 0; w < W; ++w) {
            int j = w * 64 + lane;
            bool jv = j < n;
            float4 bj = jv ? bx4[j] : make_float4(0.f, 0.f, 0.f, 0.f);
            float aj = jv ? area_s[j] : 0.f;
            for (int i = 0; i < n; ++i) {
                float4 bi = bx4[i];            // ds_read_b128 broadcast
                float ai = area_s[i];
                float xx1 = fmaxf(bi.x, bj.x), yy1 = fmaxf(bi.y, bj.y);
                float xx2 = fminf(bi.z, bj.z), yy2 = fminf(bi.w, bj.w);
                float inter = fmaxf(xx2 - xx1, 0.f) * fmaxf(yy2 - yy1, 0.f);
                bool sup = jv && (j > i) &&
                           (inter / fmaxf(ai + aj - inter, 1e-9f) > 0.5f);
                u64 m = __ballot(sup);
                if (lane == 0) Mrow[i * W + w] = m;
            }
        }
        __syncthreads();

        u64 keep_w = 0;
        if (lane < W) {
            int rem = n - lane * 64;
            keep_w = (rem >= 64) ? ~0ull : ((1ull << rem) - 1ull);
        }
        const int lw = (lane < W) ? lane : 0;
        u64 fifo[8];
#pragma unroll
        for (int d = 0; d < 8; ++d) fifo[d] = (d < n) ? Mrow[d * W + lw] : 0ull;
        for (int ib = 0; ib < n; ib += 8) {
#pragma unroll
            for (int d = 0; d < 8; ++d) {
                int i = ib + d;
                if (i >= n) break;
                u64 row = fifo[d];
                int ip = i + 8;
                fifo[d] = (ip < n) ? Mrow[ip * W + lw] : 0ull;   // prefetch (hides LDS latency)
                u64 kw = __shfl(keep_w, i >> 6);
                if ((kw >> (i & 63)) & 1ull) keep_w &= ~row;
            }
        }
        if (lane < W) keep_words[lane] = keep_w;
    } else {
        // ---- fallback: original serial greedy loop (n > NMAX never expected here)
        int* keep = (int*)poolA;
        for (int j = lane; j < n; j += 64) keep[j] = 1;
        __syncthreads();
        for (int i = 0; i < n - 1; ++i) {
            __syncthreads();
            if (!keep[i]) continue;
            float4 bi = bx4[i];
            float ai = area_s[i];
            for (int j = i + 1 + lane; j < n; j += 64) {
                if (!keep[j]) continue;
                float xx1 = fmaxf(bi.x, bx4[j].x), yy1 = fmaxf(bi.y, bx4[j].y);
                float xx2 = fminf(bi.z, bx4[j].z), yy2 = fminf(bi.w, bx4[j].w);
                float inter = fmaxf(xx2 - xx1, 0.f) * fmaxf(yy2 - yy1, 0.f);
                if (inter / fmaxf(ai + area_s[j] - inter, 1e-9f) > 0.5f) keep[j] = 0;
            }
        }
        __syncthreads();
        for (int w = 0; w * 64 < n; ++w) {
            int j = w * 64 + lane;
            u64 m = __ballot((j < n) && keep[j]);
            if (lane == 0) keep_words[w] = m;
        }
    }
    __syncthreads();

    // emit first <=100 kept, zero-pad remaining class slots
    int kb = 0;
    for (int j0 = 0; j0 < n; j0 += 64) {
        int j = j0 + lane;
        u64 mw = keep_words[j0 >> 6];
        bool kp = (j < n) && ((mw >> lane) & 1ull);
        u64 mm = __ballot(kp);
        int kr = kb + __popcll(mm & below);
        if (kp && kr < CSTR) {
            u64 kj = key_s[j];
            u32 osc = (u32)(kj >> 32);
            int rr = (R_N - 1) - (int)(kj & 0xFFFFFFFFull);
            int flat = c * R_N + j;
            cand[c * CSTR + kr] = ((u64)osc << 27) | ((u64)(u32)(131071 - flat) << 10) | (u64)(u32)rr;
        }
        kb += __popcll(mm);
    }
    if (kb > CSTR) kb = CSTR;
    for (int k2 = kb + lane; k2 < CSTR; k2 += 64) cand[c * CSTR + k2] = 0;
}

// ---------------- kernel 3: global rank via 8-way-interleaved binary searches ----------------
__global__ __launch_bounds__(256) void k_rank(const void* __restrict__ boxes,
                                              const void* __restrict__ scores,
                                              const u64* __restrict__ cand,
                                              void* __restrict__ out_p) {
    __shared__ u64 keysL[K_N * CSTR + 1];      // +1 pad for converged-search reads
    __shared__ int rankL[CSTR];
    const int c = blockIdx.x, tid = threadIdx.x;
    const bool f32m = detect_f32(scores);

    for (int t = tid; t < K_N * CSTR; t += 256) keysL[t] = cand[t];
    if (tid == 0) keysL[K_N * CSTR] = 0;
    if (tid < CSTR) rankL[tid] = 0;
    __syncthreads();

    // 8000 tasks (cand i of class c  x  class-list cc); 8 interleaved search states/thread
    for (int g = 0; g < 4; ++g) {
        int lo[8], hi[8], ii[8];
        u64 xv[8];
        const u64* Lp[8];
        bool act[8];
#pragma unroll
        for (int s = 0; s < 8; ++s) {
            int t = tid + 256 * (g * 8 + s);
            act[s] = t < CSTR * K_N;
            int i = 0, cc = 0;
            if (act[s]) { i = t / K_N; cc = t - i * K_N; }
            ii[s] = i;
            xv[s] = keysL[c * CSTR + i];
            Lp[s] = keysL + cc * CSTR;
            if (xv[s] == 0ull) act[s] = false;
            lo[s] = 0; hi[s] = CSTR;
        }
#pragma unroll
        for (int st = 0; st < 8; ++st) {
#pragma unroll
            for (int s = 0; s < 8; ++s) {
                int mid = (lo[s] + hi[s]) >> 1;
                u64 v = Lp[s][mid];            // 8 independent LDS reads per step
                bool live = lo[s] < hi[s];
                bool gt = live && (v > xv[s]);
                lo[s] = gt ? mid + 1 : lo[s];
                hi[s] = (live && !gt) ? mid : hi[s];
            }
        }
#pragma unroll
        for (int s = 0; s < 8; ++s)
            if (act[s] && lo[s] > 0) atomicAdd(&rankL[ii[s]], lo[s]);
    }
    __syncthreads();

    // winners (global rank < 100) write their output row; rows beyond stay zero (k_stat)
    if (tid < CSTR) {
        u64 x = keysL[c * CSTR + tid];
        int rank = rankL[tid];
        if (x != 0ull && rank < TOPK_N) {
            int prop = (int)(x & 0x3FFull);
            float score = f32_unorder((u32)((x >> 27) & 0xFFFFFFFFull));
            int ob = rank * OUT_W;
            float4 bx = ld4(boxes, prop * (K_N * 4) + c * 4, f32m);
            stv(out_p, ob + 0, fminf(fmaxf(bx.x, 0.f), IMG_W_), f32m);
            stv(out_p, ob + 1, fminf(fmaxf(bx.y, 0.f), IMG_H_), f32m);
            stv(out_p, ob + 2, fminf(fmaxf(bx.z, 0.f), IMG_W_), f32m);
            stv(out_p, ob + 3, fminf(fmaxf(bx.w, 0.f), IMG_H_), f32m);
            stv(out_p, ob + 4, score, f32m);
            stv(out_p, ob + 5, (float)c, f32m);
            const int sb = prop * NCOL;
#pragma unroll 9
            for (int j = 0; j < NCOL; ++j)
                stv(out_p, ob + 6 + j, ldv(scores, sb + j, f32m), f32m);
        }
    }
}

extern "C" void kernel_launch(void* const* d_in, const int* in_sizes, int n_in,
                              void* d_out, int out_size, void* d_ws, size_t ws_size,
                              hipStream_t stream) {
    const void* boxes = d_in[0];
    const void* scores = d_in[1];
    float* hdr = (float*)d_ws;                 // 160 f32 partials
    u64* cand = (u64*)((char*)d_ws + 1024);    // 80*100 u64

    k_stat<<<K_N, 256, 0, stream>>>(scores, hdr, d_out);
    k_nms<<<K_N, 64, 0, stream>>>(boxes, scores, hdr, cand);
    k_rank<<<K_N, 256, 0, stream>>>(boxes, scores, cand, d_out);
}